// Round 5
// baseline (917.929 us; speedup 1.0000x reference)
//
#include <hip/hip_runtime.h>
#include <hip/hip_bf16.h>

// LSTMAggregator — ROUND 5: R2's MFMA kernel (cross-validated against the
// scalar R3 kernel: bit-identical absmax) with the one real bug fixed:
// OUTPUT IS F32 (reference returns float32; harness gives float* d_out).
// R2/R3/R4 wrote bf16 into the f32 buffer -> misplaced values, absmax 0.219.
//
// Inputs: nidx int32, all float tensors f32. Weights pre-converted f32->bf16
// into d_ws; x A-fragments converted f32->bf16 in-register after gather.
//
// One wave = 16 nodes, full 256-gate width via mfma_f32_16x16x32_bf16.
//   A-frag: A[m=lane&15][k=(lane>>4)*8+j]
//   B-frag: B[k][n=lane&15] = W[gate=16t+(lane&15)][k]
//   C/D:    row(node)=(lane>>4)*4+reg, col(gate)=lane&15
// h state round-trips through a private per-wave LDS region (row stride 144 B
// to avoid stride-128B bank patterns on A-frag reads).

#define NN 50000
#define KK 10
#define FF 128
#define HH 64

// ws layout (bf16 elements)
#define WS_WIH_F 0
#define WS_WHH_F 32768
#define WS_WIH_B 49152

typedef __bf16 bf16x8 __attribute__((ext_vector_type(8)));
typedef float f32x4 __attribute__((ext_vector_type(4)));

__device__ __forceinline__ float fast_sig(float x) {
    float e = exp2f(x * -1.44269504f);
    return __builtin_amdgcn_rcpf(1.0f + e);
}

__device__ __forceinline__ float fast_tanh(float x) {
    float xx = fminf(fmaxf(x, -15.0f), 15.0f);
    float e = exp2f(xx * 2.88539008f);
    return (e - 1.0f) * __builtin_amdgcn_rcpf(e + 1.0f);
}

__device__ __forceinline__ bf16x8 load_cvt8(const float* p) {
    f32x4 lo = *(const f32x4*)p;
    f32x4 hi = *(const f32x4*)(p + 4);
    bf16x8 r;
#pragma unroll
    for (int j = 0; j < 4; ++j) { r[j] = (__bf16)lo[j]; r[4 + j] = (__bf16)hi[j]; }
    return r;
}

__global__ void cvt_weights_kernel(const float* __restrict__ Wih_f,
                                   const float* __restrict__ Whh_f,
                                   const float* __restrict__ Wih_b,
                                   __bf16* __restrict__ ws) {
    int i = blockIdx.x * 256 + threadIdx.x;          // 32768 threads
    ws[WS_WIH_F + i] = (__bf16)Wih_f[i];
    if (i < 16384) ws[WS_WHH_F + i] = (__bf16)Whh_f[i];
    ws[WS_WIH_B + i] = (__bf16)Wih_b[i];
}

__global__ __launch_bounds__(256, 2) void lstm_agg_kernel(
    const int* __restrict__ nidx,
    const float* __restrict__ tab,
    const float* __restrict__ bih_f,
    const float* __restrict__ bhh_f,
    const float* __restrict__ bih_b,
    const float* __restrict__ bhh_b,
    const __bf16* __restrict__ ws,
    float* __restrict__ out)
{
    __shared__ __bf16 h_lds[4][16 * 72];   // per-wave private, 144 B row stride

    const __bf16* Wih_f = ws + WS_WIH_F;
    const __bf16* Whh_f = ws + WS_WHH_F;
    const __bf16* Wih_b = ws + WS_WIH_B;

    const int tid  = threadIdx.x;
    const int wid  = tid >> 6;
    const int lane = tid & 63;
    const int q    = lane >> 4;     // quad id
    const int c    = lane & 15;     // A-row (node) for A-frags; C/D col (gate) for acc
    const int koff = q * 8;         // element offset of this quad within a 32-chunk

    const int node_base = blockIdx.x * 64 + wid * 16;

    const int safe_arow = min(node_base + c, NN - 1);
    int gidx[KK];
#pragma unroll
    for (int k = 0; k < KK; ++k) gidx[k] = nidx[safe_arow * KK + k];

    // ---------------- backward direction: one step on x[:,9], zero state ------
    {
        float bias_b[12];
#pragma unroll
        for (int tt = 0; tt < 12; ++tt) {
            int t = (tt < 4) ? tt : tt + 4;          // skip f-gate tiles 4..7
            int g = t * 16 + c;
            bias_b[tt] = bih_b[g] + bhh_b[g];
        }
        f32x4 acc[12];
#pragma unroll
        for (int tt = 0; tt < 12; ++tt)
            acc[tt] = (f32x4){bias_b[tt], bias_b[tt], bias_b[tt], bias_b[tt]};

        const float* xrow = tab + (size_t)gidx[KK - 1] * FF;
#pragma unroll
        for (int kk = 0; kk < 4; ++kk) {
            bf16x8 a = load_cvt8(xrow + kk * 32 + koff);
#pragma unroll
            for (int tt = 0; tt < 12; ++tt) {
                int t = (tt < 4) ? tt : tt + 4;
                bf16x8 b = *(const bf16x8*)(Wih_b + (t * 16 + c) * FF + kk * 32 + koff);
                acc[tt] = __builtin_amdgcn_mfma_f32_16x16x32_bf16(a, b, acc[tt], 0, 0, 0);
            }
        }
#pragma unroll
        for (int a4 = 0; a4 < 4; ++a4) {
#pragma unroll
            for (int reg = 0; reg < 4; ++reg) {
                float gi = fast_sig(acc[a4][reg]);
                float gg = fast_tanh(acc[4 + a4][reg]);
                float go = fast_sig(acc[8 + a4][reg]);
                float cb = gi * gg;                   // c0 = 0 -> f-gate irrelevant
                float hb = go * fast_tanh(cb);
                int node = node_base + q * 4 + reg;
                if (node < NN)
                    out[(size_t)node * 128 + 64 + a4 * 16 + c] = hb;
            }
        }
    }

    // ---------------- forward direction: 10-step recurrence -------------------
    float bias_f[16];
#pragma unroll
    for (int t = 0; t < 16; ++t) {
        int g = t * 16 + c;
        bias_f[t] = bih_f[g] + bhh_f[g];
    }

    float cst[4][4];
#pragma unroll
    for (int a4 = 0; a4 < 4; ++a4)
#pragma unroll
        for (int reg = 0; reg < 4; ++reg) cst[a4][reg] = 0.0f;

    for (int k = 0; k < KK; ++k) {
        f32x4 acc[16];
#pragma unroll
        for (int t = 0; t < 16; ++t)
            acc[t] = (f32x4){bias_f[t], bias_f[t], bias_f[t], bias_f[t]};

        // x_k @ Wih_f^T
        const float* xrow = tab + (size_t)gidx[k] * FF;
#pragma unroll
        for (int kk = 0; kk < 4; ++kk) {
            bf16x8 a = load_cvt8(xrow + kk * 32 + koff);
#pragma unroll
            for (int t = 0; t < 16; ++t) {
                bf16x8 b = *(const bf16x8*)(Wih_f + (t * 16 + c) * FF + kk * 32 + koff);
                acc[t] = __builtin_amdgcn_mfma_f32_16x16x32_bf16(a, b, acc[t], 0, 0, 0);
            }
        }

        // h_{k-1} @ Whh_f^T (h==0 at k=0: skip)
        if (k > 0) {
#pragma unroll
            for (int kk = 0; kk < 2; ++kk) {
                bf16x8 ah = *(const bf16x8*)(&h_lds[wid][c * 72 + kk * 32 + koff]);
#pragma unroll
                for (int t = 0; t < 16; ++t) {
                    bf16x8 b = *(const bf16x8*)(Whh_f + (t * 16 + c) * HH + kk * 32 + koff);
                    acc[t] = __builtin_amdgcn_mfma_f32_16x16x32_bf16(ah, b, acc[t], 0, 0, 0);
                }
            }
        }

        // activations: lane-local (i,f,g,o for unit 16*a4+c live in tiles a4,4+a4,8+a4,12+a4)
        const bool last = (k == KK - 1);
#pragma unroll
        for (int a4 = 0; a4 < 4; ++a4) {
#pragma unroll
            for (int reg = 0; reg < 4; ++reg) {
                float gi = fast_sig(acc[a4][reg]);
                float gf = fast_sig(acc[4 + a4][reg]);
                float gg = fast_tanh(acc[8 + a4][reg]);
                float go = fast_sig(acc[12 + a4][reg]);
                float cn = gf * cst[a4][reg] + gi * gg;
                cst[a4][reg] = cn;
                float h = go * fast_tanh(cn);
                if (last) {
                    int node = node_base + q * 4 + reg;
                    if (node < NN)
                        out[(size_t)node * 128 + a4 * 16 + c] = h;
                } else {
                    h_lds[wid][(q * 4 + reg) * 72 + a4 * 16 + c] = (__bf16)h;
                }
            }
        }
        __syncthreads();   // order h writes (step k) before A-frag reads (step k+1)
    }
}

extern "C" void kernel_launch(void* const* d_in, const int* in_sizes, int n_in,
                              void* d_out, int out_size, void* d_ws, size_t ws_size,
                              hipStream_t stream) {
    const int*   nidx  = (const int*)d_in[0];
    const float* tab   = (const float*)d_in[1];
    const float* Wih_f = (const float*)d_in[2];
    const float* Whh_f = (const float*)d_in[3];
    const float* bih_f = (const float*)d_in[4];
    const float* bhh_f = (const float*)d_in[5];
    const float* Wih_b = (const float*)d_in[6];
    // d_in[7] = Whh_b: mathematically unused (h0 = 0 for the backward stream)
    const float* bih_b = (const float*)d_in[8];
    const float* bhh_b = (const float*)d_in[9];
    __bf16* ws  = (__bf16*)d_ws;      // needs 81920*2 = 160 KB of scratch
    float*  out = (float*)d_out;      // OUTPUT IS F32 (reference returns float32)

    hipLaunchKernelGGL(cvt_weights_kernel, dim3(32768 / 256), dim3(256), 0, stream,
                       Wih_f, Whh_f, Wih_b, ws);

    const int blocks = (NN + 63) / 64;   // 64 nodes per 256-thread block (4 waves x 16)
    hipLaunchKernelGGL(lstm_agg_kernel, dim3(blocks), dim3(256), 0, stream,
                       nidx, tab, bih_f, bhh_f, bih_b, bhh_b, ws, out);
}

// Round 6
// 373.498 us; speedup vs baseline: 2.4577x; 2.4577x over previous
//
#include <hip/hip_runtime.h>
#include <hip/hip_bf16.h>

// LSTMAggregator — ROUND 6: weight-resident restructure.
// R5 passed (absmax 9.8e-4) but was latency/traffic-bound: each wave re-read
// 96 KB of weights from global EVERY step (~3 GB total), thrashing L2 against
// the 256 MB random gather -> FETCH 1.33 GB, MfmaUtil 2.5%, 795 us.
//
// R6: block = 256 threads = 64 nodes (4 groups of 16). Wave w owns gate-tiles
// {g*4+w | g in i,f,g,o} = all 4 gates of hidden units w*16..w*16+15, for ALL
// 64 nodes. Weight B-fragments (Wih_f 16, Whh_f 8 per lane) live in REGISTERS
// for the whole kernel -> zero weight traffic in the K-loop. x rows are
// cooperatively staged (coalesced f32 loads, one-step register prefetch) into
// bf16 LDS; h round-trips through LDS with a padded stride.
//   A-frag: A[m=lane&15][k=(lane>>4)*8+j]   B-frag: B[k][n=lane&15]=W[row][k]
//   C/D: row(node-in-group)=(lane>>4)*4+reg, col=lane&15 -> unit w*16+(lane&15)
// Activations lane-local (all 4 gates of a unit in the same lane/reg).

#define NN 50000
#define KK 10
#define FF 128
#define HH 64

// ws layout (bf16 elements)
#define WS_WIH_F 0
#define WS_WHH_F 32768
#define WS_WIH_B 49152

#define XS 136   // x_lds row stride (shorts): 128+8 pad -> frag reads spread banks
#define HS 72    // h_lds row stride (shorts): 64+8 pad

typedef __bf16 bf16x8 __attribute__((ext_vector_type(8)));
typedef float f32x4 __attribute__((ext_vector_type(4)));

__device__ __forceinline__ float fast_sig(float x) {
    float e = exp2f(x * -1.44269504f);
    return __builtin_amdgcn_rcpf(1.0f + e);
}
__device__ __forceinline__ float fast_tanh(float x) {
    float xx = fminf(fmaxf(x, -15.0f), 15.0f);
    float e = exp2f(xx * 2.88539008f);
    return (e - 1.0f) * __builtin_amdgcn_rcpf(e + 1.0f);
}

__global__ void cvt_weights_kernel(const float* __restrict__ Wih_f,
                                   const float* __restrict__ Whh_f,
                                   const float* __restrict__ Wih_b,
                                   __bf16* __restrict__ ws) {
    int i = blockIdx.x * 256 + threadIdx.x;          // 32768 threads
    ws[WS_WIH_F + i] = (__bf16)Wih_f[i];
    if (i < 16384) ws[WS_WHH_F + i] = (__bf16)Whh_f[i];
    ws[WS_WIH_B + i] = (__bf16)Wih_b[i];
}

__global__ __launch_bounds__(256, 2) void lstm_agg_kernel(
    const int* __restrict__ nidx,
    const float* __restrict__ tab,
    const float* __restrict__ bih_f,
    const float* __restrict__ bhh_f,
    const float* __restrict__ bih_b,
    const float* __restrict__ bhh_b,
    const __bf16* __restrict__ ws,
    float* __restrict__ out)
{
    __shared__ __bf16 x_lds[64 * XS];   // 17408 B
    __shared__ __bf16 h_lds[64 * HS];   //  9216 B
    __shared__ int    gq[64][KK];       //  2560 B

    const int tid  = threadIdx.x;
    const int w    = tid >> 6;        // wave id: owns units w*16..w*16+15
    const int lane = tid & 63;
    const int q    = lane >> 4;
    const int c    = lane & 15;
    const int koff = q * 8;
    const int node_base = blockIdx.x * 64;

    // stage gather indices for the block's 64 nodes
    for (int i = tid; i < 64 * KK; i += 256) {
        int r = i / KK, k = i - r * KK;
        int node = min(node_base + r, NN - 1);
        gq[r][k] = nidx[node * KK + k];
    }

    // weight B-fragments, register-resident for the whole kernel
    bf16x8 bWih[4][4], bWhh[4][2];
#pragma unroll
    for (int g = 0; g < 4; ++g) {
        int row = (g * 4 + w) * 16 + c;        // gate row g*64 + w*16 + c
#pragma unroll
        for (int kk = 0; kk < 4; ++kk)
            bWih[g][kk] = *(const bf16x8*)(ws + WS_WIH_F + row * FF + kk * 32 + koff);
#pragma unroll
        for (int kk = 0; kk < 2; ++kk)
            bWhh[g][kk] = *(const bf16x8*)(ws + WS_WHH_F + row * HH + kk * 32 + koff);
    }

    float bias[4];
#pragma unroll
    for (int g = 0; g < 4; ++g) {
        int u = g * 64 + w * 16 + c;
        bias[g] = bih_f[u] + bhh_f[u];
    }

    __syncthreads();   // gq visible

    // x staging: thread -> (row = tid>>2, quarter p = tid&3) : 32 f32 each
    const int srow = tid >> 2, spart = tid & 3;

    f32x4 R[8];   // prefetched f32 x data for the upcoming step
    {
        const float* src = tab + (size_t)gq[srow][0] * FF + spart * 32;
#pragma unroll
        for (int j = 0; j < 8; ++j) R[j] = *(const f32x4*)(src + j * 4);
    }

    f32x4 acc[4][4];      // [gate][group]
    float cst[4][4];      // [group][reg] cell state
    float hreg[4][4];     // [group][reg] h of current step
#pragma unroll
    for (int r = 0; r < 4; ++r)
#pragma unroll
        for (int reg = 0; reg < 4; ++reg) cst[r][reg] = 0.0f;

    for (int k = 0; k < KK; ++k) {
        // ---- phase A: write x_k to LDS (cvt), write h_{k-1}, prefetch x_{k+1}
        {
            __bf16* dst = x_lds + srow * XS + spart * 32;
#pragma unroll
            for (int jj = 0; jj < 4; ++jj) {
                bf16x8 v;
#pragma unroll
                for (int e = 0; e < 4; ++e) {
                    v[e]     = (__bf16)R[jj * 2][e];
                    v[4 + e] = (__bf16)R[jj * 2 + 1][e];
                }
                *(bf16x8*)(dst + jj * 8) = v;
            }
        }
        if (k > 0) {
#pragma unroll
            for (int r = 0; r < 4; ++r)
#pragma unroll
                for (int reg = 0; reg < 4; ++reg)
                    h_lds[(r * 16 + q * 4 + reg) * HS + w * 16 + c] = (__bf16)hreg[r][reg];
        }
        if (k + 1 < KK) {
            const float* src = tab + (size_t)gq[srow][k + 1] * FF + spart * 32;
#pragma unroll
            for (int j = 0; j < 8; ++j) R[j] = *(const f32x4*)(src + j * 4);
        }
        __syncthreads();

        // ---- phase B: MFMAs + activations
#pragma unroll
        for (int g = 0; g < 4; ++g)
#pragma unroll
            for (int r = 0; r < 4; ++r)
                acc[g][r] = (f32x4){bias[g], bias[g], bias[g], bias[g]};

#pragma unroll
        for (int r = 0; r < 4; ++r) {
            bf16x8 xa[4];
#pragma unroll
            for (int kk = 0; kk < 4; ++kk)
                xa[kk] = *(const bf16x8*)(x_lds + (r * 16 + c) * XS + kk * 32 + koff);
#pragma unroll
            for (int g = 0; g < 4; ++g)
#pragma unroll
                for (int kk = 0; kk < 4; ++kk)
                    acc[g][r] = __builtin_amdgcn_mfma_f32_16x16x32_bf16(
                        xa[kk], bWih[g][kk], acc[g][r], 0, 0, 0);
        }
        if (k > 0) {
#pragma unroll
            for (int r = 0; r < 4; ++r) {
                bf16x8 ha[2];
#pragma unroll
                for (int kk = 0; kk < 2; ++kk)
                    ha[kk] = *(const bf16x8*)(h_lds + (r * 16 + c) * HS + kk * 32 + koff);
#pragma unroll
                for (int g = 0; g < 4; ++g)
#pragma unroll
                    for (int kk = 0; kk < 2; ++kk)
                        acc[g][r] = __builtin_amdgcn_mfma_f32_16x16x32_bf16(
                            ha[kk], bWhh[g][kk], acc[g][r], 0, 0, 0);
            }
        }

        const bool last = (k == KK - 1);
#pragma unroll
        for (int r = 0; r < 4; ++r)
#pragma unroll
            for (int reg = 0; reg < 4; ++reg) {
                float gi = fast_sig(acc[0][r][reg]);
                float gf = fast_sig(acc[1][r][reg]);
                float gg = fast_tanh(acc[2][r][reg]);
                float go = fast_sig(acc[3][r][reg]);
                float cn = gf * cst[r][reg] + gi * gg;
                cst[r][reg] = cn;
                float h = go * fast_tanh(cn);
                hreg[r][reg] = h;
                if (last) {
                    int node = node_base + r * 16 + q * 4 + reg;
                    if (node < NN) out[(size_t)node * 128 + w * 16 + c] = h;
                }
            }
        __syncthreads();   // phase-B LDS reads done before next phase-A writes
    }

    // ---- backward direction: one step on x[:,9] (still in x_lds), zero state
    {
        const int gb[3] = {0, 2, 3};    // gates i, g, o (f irrelevant: c0 = 0)
        bf16x8 bW[3][4];
        float  bb[3];
#pragma unroll
        for (int j = 0; j < 3; ++j) {
            int row = (gb[j] * 4 + w) * 16 + c;
#pragma unroll
            for (int kk = 0; kk < 4; ++kk)
                bW[j][kk] = *(const bf16x8*)(ws + WS_WIH_B + row * FF + kk * 32 + koff);
            int u = gb[j] * 64 + w * 16 + c;
            bb[j] = bih_b[u] + bhh_b[u];
        }
#pragma unroll
        for (int r = 0; r < 4; ++r) {
            f32x4 a0 = (f32x4){bb[0], bb[0], bb[0], bb[0]};
            f32x4 a1 = (f32x4){bb[1], bb[1], bb[1], bb[1]};
            f32x4 a2 = (f32x4){bb[2], bb[2], bb[2], bb[2]};
            bf16x8 xa[4];
#pragma unroll
            for (int kk = 0; kk < 4; ++kk)
                xa[kk] = *(const bf16x8*)(x_lds + (r * 16 + c) * XS + kk * 32 + koff);
#pragma unroll
            for (int kk = 0; kk < 4; ++kk) {
                a0 = __builtin_amdgcn_mfma_f32_16x16x32_bf16(xa[kk], bW[0][kk], a0, 0, 0, 0);
                a1 = __builtin_amdgcn_mfma_f32_16x16x32_bf16(xa[kk], bW[1][kk], a1, 0, 0, 0);
                a2 = __builtin_amdgcn_mfma_f32_16x16x32_bf16(xa[kk], bW[2][kk], a2, 0, 0, 0);
            }
#pragma unroll
            for (int reg = 0; reg < 4; ++reg) {
                float gi = fast_sig(a0[reg]);
                float gg = fast_tanh(a1[reg]);
                float go = fast_sig(a2[reg]);
                float hb = go * fast_tanh(gi * gg);
                int node = node_base + r * 16 + q * 4 + reg;
                if (node < NN) out[(size_t)node * 128 + 64 + w * 16 + c] = hb;
            }
        }
    }
}

extern "C" void kernel_launch(void* const* d_in, const int* in_sizes, int n_in,
                              void* d_out, int out_size, void* d_ws, size_t ws_size,
                              hipStream_t stream) {
    const int*   nidx  = (const int*)d_in[0];
    const float* tab   = (const float*)d_in[1];
    const float* Wih_f = (const float*)d_in[2];
    const float* Whh_f = (const float*)d_in[3];
    const float* bih_f = (const float*)d_in[4];
    const float* bhh_f = (const float*)d_in[5];
    const float* Wih_b = (const float*)d_in[6];
    // d_in[7] = Whh_b: mathematically unused (h0 = 0 for the backward stream)
    const float* bih_b = (const float*)d_in[8];
    const float* bhh_b = (const float*)d_in[9];
    __bf16* ws  = (__bf16*)d_ws;      // 160 KB scratch
    float*  out = (float*)d_out;      // output is f32

    hipLaunchKernelGGL(cvt_weights_kernel, dim3(32768 / 256), dim3(256), 0, stream,
                       Wih_f, Whh_f, Wih_b, ws);

    const int blocks = (NN + 63) / 64;   // 64 nodes per 256-thread block
    hipLaunchKernelGGL(lstm_agg_kernel, dim3(blocks), dim3(256), 0, stream,
                       nidx, tab, bih_f, bhh_f, bih_b, bhh_b, ws, out);
}